// Round 8
// baseline (281.289 us; speedup 1.0000x reference)
//
#include <hip/hip_runtime.h>
#include <hip/hip_bf16.h>

// Problem dims (fixed by reference)
#define B_    8
#define C_    512
#define HW_   1024     // H*W = 32*32
#define NG    32
#define GCH   16
#define EPSV  1e-6f

typedef __attribute__((ext_vector_type(8))) short short8;   // 8 bf16 (4 VGPRs)
typedef __attribute__((ext_vector_type(4))) short short4v;  // 4 bf16
typedef __attribute__((ext_vector_type(4))) float floatx4;  // MFMA C/D

static __device__ __forceinline__ short f2bs(float f) {
  return __builtin_bit_cast(short, __float2bfloat16(f));
}
static __device__ __forceinline__ short4v pack4(float a, float b, float c, float d) {
  return (short4v){f2bs(a), f2bs(b), f2bs(c), f2bs(d)};
}
#define MFMA(a, b, c) __builtin_amdgcn_mfma_f32_16x16x32_bf16((a), (b), (c), 0, 0, 0)

// ---------------------------------------------------------------------------
// fp32 -> bf16 cast (weights); 4 elems/thread
// ---------------------------------------------------------------------------
__global__ __launch_bounds__(256) void cast_f2b(const float* __restrict__ s,
                                                short* __restrict__ d) {
  int i = blockIdx.x * 256 + threadIdx.x;
  float4 v = reinterpret_cast<const float4*>(s)[i];
  reinterpret_cast<short4v*>(d)[i] = pack4(v.x, v.y, v.z, v.w);
}

// ---------------------------------------------------------------------------
// Kernel 1a: GroupNorm stats.  One block per (b, group) -> {mean, rsig}.
// ---------------------------------------------------------------------------
__global__ __launch_bounds__(256) void gn_stats(
    const float* __restrict__ x, float2* __restrict__ stats) {
  int bg = blockIdx.x;
  const int n = GCH * HW_;       // 16384
  const float* xp = x + (size_t)bg * n;
  int t = threadIdx.x;

  float s = 0.f, ss = 0.f;
  for (int i = t; i < n / 4; i += 256) {   // i indexes float4s
    float4 v = *reinterpret_cast<const float4*>(xp + i * 4);
    s  += (v.x + v.y) + (v.z + v.w);
    ss += (v.x * v.x + v.y * v.y) + (v.z * v.z + v.w * v.w);
  }
  for (int o = 32; o > 0; o >>= 1) {
    s  += __shfl_down(s, o);
    ss += __shfl_down(ss, o);
  }
  __shared__ float rs_[4], rss_[4];
  int wid = t >> 6, lane = t & 63;
  if (lane == 0) { rs_[wid] = s; rss_[wid] = ss; }
  __syncthreads();
  if (t == 0) {
    float stot  = rs_[0] + rs_[1] + rs_[2] + rs_[3];
    float sstot = rss_[0] + rss_[1] + rss_[2] + rss_[3];
    float mean = stot / (float)n;
    float var  = sstot / (float)n - mean * mean;
    stats[bg] = make_float2(mean, rsqrtf(var + EPSV));
  }
}

// ---------------------------------------------------------------------------
// Kernel 1b: normalize + transpose -> ht[b][seq][ch] bf16.
// Block = (seq-tile 64, ch-tile 64, b).  LDS float[64][65].
// ---------------------------------------------------------------------------
__global__ __launch_bounds__(256) void gn_apply(
    const float* __restrict__ x, const float2* __restrict__ stats,
    const float* __restrict__ gamma, const float* __restrict__ beta,
    short* __restrict__ ht) {
  __shared__ float Ls[64 * 65];
  int s0 = blockIdx.x * 64, ch0 = blockIdx.y * 64, b = blockIdx.z;
  int t = threadIdx.x;

  for (int i = 0; i < 4; i++) {
    int lin = t + i * 256;           // 64 rows x 16 float4
    int r = lin >> 4, c4 = lin & 15;
    int ch = ch0 + r;
    float2 st = stats[b * NG + (ch >> 4)];
    float ga = gamma[ch] * st.y;     // fold rsig into gamma
    float be = beta[ch] - st.x * ga;
    float4 v = *reinterpret_cast<const float4*>(
        x + ((size_t)(b * C_ + ch)) * HW_ + s0 + c4 * 4);
    Ls[r * 65 + c4 * 4 + 0] = v.x * ga + be;
    Ls[r * 65 + c4 * 4 + 1] = v.y * ga + be;
    Ls[r * 65 + c4 * 4 + 2] = v.z * ga + be;
    Ls[r * 65 + c4 * 4 + 3] = v.w * ga + be;
  }
  __syncthreads();
  for (int i = 0; i < 4; i++) {
    int lin = t + i * 256;           // 64 seq x 16 short4
    int sq = lin >> 4, cq = lin & 15;
    float a0 = Ls[(cq * 4 + 0) * 65 + sq];
    float a1 = Ls[(cq * 4 + 1) * 65 + sq];
    float a2 = Ls[(cq * 4 + 2) * 65 + sq];
    float a3 = Ls[(cq * 4 + 3) * 65 + sq];
    *reinterpret_cast<short4v*>(
        ht + ((size_t)b * 1024 + s0 + sq) * 512 + ch0 + cq * 4) =
        pack4(a0, a1, a2, a3);
  }
}

// ---------------------------------------------------------------------------
// Kernel 2: LDS-free MFMA QKV GEMM.
//   Output: m<512 -> Qt[b][h][seq][64] (x 0.125*log2e folded -> exp2 softmax),
//           m<1024 -> Kt same, m>=1024 -> Vn[b][ch][seq] natural.
// ---------------------------------------------------------------------------
__global__ __launch_bounds__(256) void gemm_qkv(
    const short* __restrict__ Wb, const short* __restrict__ ht,
    const float* __restrict__ bias,
    short* __restrict__ Qt, short* __restrict__ Kt, short* __restrict__ Vn) {
  int bx = blockIdx.x, by = blockIdx.y, bb = blockIdx.z;
  int m0 = by * 128, n0 = bx * 128;
  int t = threadIdx.x;
  int w = t >> 6, lane = t & 63, n16 = lane & 15, quad = lane >> 4;
  int wm = (w >> 1) * 64, wn = (w & 1) * 64;

  const short* Ab[4];
  const short* Bb[4];
  for (int im = 0; im < 4; im++)
    Ab[im] = Wb + (size_t)(m0 + wm + im * 16 + n16) * 512 + quad * 8;
  const short* Xb = ht + (size_t)bb * 1024 * 512;
  for (int in = 0; in < 4; in++)
    Bb[in] = Xb + (size_t)(n0 + wn + in * 16 + n16) * 512 + quad * 8;

  floatx4 acc[4][4];
  for (int i = 0; i < 4; i++)
    for (int j = 0; j < 4; j++) acc[i][j] = (floatx4){0.f, 0.f, 0.f, 0.f};

#pragma unroll 2
  for (int kk = 0; kk < 512; kk += 32) {
    short8 a[4], b[4];
    for (int im = 0; im < 4; im++)
      a[im] = *reinterpret_cast<const short8*>(Ab[im] + kk);
    for (int in = 0; in < 4; in++)
      b[in] = *reinterpret_cast<const short8*>(Bb[in] + kk);
    for (int im = 0; im < 4; im++)
      for (int in = 0; in < 4; in++)
        acc[im][in] = MFMA(a[im], b[in], acc[im][in]);
  }

  if (m0 < 1024) {                 // Q or K: transposed store [seq][d]
    const bool isQ = (m0 < 512);
    short* base = isQ ? Qt : Kt;
    // Q scale = 1/sqrt(64) * log2(e)  (softmax computed in base 2)
    const float sc = isQ ? 0.180336880111120426f : 1.0f;
    for (int im = 0; im < 4; im++) {
      int m = m0 + wm + im * 16 + quad * 4;
      int hh = (m >> 6) & 7, d0 = m & 63;
      float4 bi = *reinterpret_cast<const float4*>(&bias[m]);
      short* hb = base + (size_t)(bb * 8 + hh) * 1024 * 64 + d0;
      for (int in = 0; in < 4; in++) {
        int nn = n0 + wn + in * 16 + n16;
        *reinterpret_cast<short4v*>(hb + (size_t)nn * 64) =
            pack4((acc[im][in][0] + bi.x) * sc, (acc[im][in][1] + bi.y) * sc,
                  (acc[im][in][2] + bi.z) * sc, (acc[im][in][3] + bi.w) * sc);
      }
    }
  } else {                         // V: natural store [ch][seq]
    for (int im = 0; im < 4; im++) {
      int m = m0 + wm + im * 16 + quad * 4;
      float4 bi = *reinterpret_cast<const float4*>(&bias[m]);
      int ch = m - 1024;
      for (int in = 0; in < 4; in++) {
        int nn = n0 + wn + in * 16 + n16;
        short* vp = Vn + (size_t)(bb * 512 + ch) * 1024 + nn;
        vp[0]    = f2bs(acc[im][in][0] + bi.x);
        vp[1024] = f2bs(acc[im][in][1] + bi.y);
        vp[2048] = f2bs(acc[im][in][2] + bi.z);
        vp[3072] = f2bs(acc[im][in][3] + bi.w);
      }
    }
  }
}

// ---------------------------------------------------------------------------
// Kernel 3: barrier-free MFMA attention, 64 q rows per block (16 per wave).
// blk = qb*64 + (b*8+h): all 16 q-blocks of a head are congruent mod 8 ->
// land on the same XCD (round-robin dispatch), so K/V stay in one L2.
// Softmax in base 2 (scale folded into Q); no max subtraction.
// P roundtrip via per-wave swizzled LDS, double-buffered by kt parity.
// ---------------------------------------------------------------------------
__global__ __launch_bounds__(256) void attn_mfma(
    const short* __restrict__ Qt, const short* __restrict__ Kt,
    const short* __restrict__ Vn, short* __restrict__ attnT) {
  __shared__ short Ps[4][2][1024];   // [wave][kt&1][16*64]  16 KB
  int blk = blockIdx.x;              // qb*64 + b*8 + h
  int bh = blk & 63, qb = blk >> 6;
  int b = bh >> 3, h = bh & 7;
  int t = threadIdx.x;
  int w = t >> 6, lane = t & 63, n16 = lane & 15, quad = lane >> 4;
  int q0 = qb * 64 + w * 16;

  const short* Qp = Qt + (size_t)bh * 1024 * 64;
  const short* Kp = Kt + (size_t)bh * 1024 * 64;
  const short* Vp = Vn + (size_t)(b * 512 + h * 64) * 1024;

  short8 qa[2];
  for (int f = 0; f < 2; f++)
    qa[f] = *reinterpret_cast<const short8*>(
        Qp + (size_t)(q0 + n16) * 64 + f * 32 + quad * 8);

  floatx4 O[4];
  float l[4];
  for (int i = 0; i < 4; i++) {
    O[i] = (floatx4){0.f, 0.f, 0.f, 0.f};
    l[i] = 0.f;
  }

  int sub = n16 & 7, hi = n16 >> 3;
  for (int kt = 0; kt < 16; kt++) {
    int k0 = kt * 64;
    short8 kf[4][2];
    for (int nt = 0; nt < 4; nt++)
      for (int f = 0; f < 2; f++)
        kf[nt][f] = *reinterpret_cast<const short8*>(
            Kp + (size_t)(k0 + nt * 16 + n16) * 64 + f * 32 + quad * 8);

    floatx4 S[4];
    for (int nt = 0; nt < 4; nt++) {
      floatx4 sa = (floatx4){0.f, 0.f, 0.f, 0.f};
      sa = MFMA(qa[0], kf[nt][0], sa);
      S[nt] = MFMA(qa[1], kf[nt][1], sa);
    }

    short* Pq = &Ps[w][kt & 1][0];
    for (int r = 0; r < 4; r++) {
      int row = quad * 4 + r;
      float p0 = __builtin_amdgcn_exp2f(S[0][r]);
      float p1 = __builtin_amdgcn_exp2f(S[1][r]);
      float p2 = __builtin_amdgcn_exp2f(S[2][r]);
      float p3 = __builtin_amdgcn_exp2f(S[3][r]);
      l[r] += (p0 + p1) + (p2 + p3);
      Pq[row * 64 + ((0 + hi + row) & 7) * 8 + sub] = f2bs(p0);
      Pq[row * 64 + ((2 + hi + row) & 7) * 8 + sub] = f2bs(p1);
      Pq[row * 64 + ((4 + hi + row) & 7) * 8 + sub] = f2bs(p2);
      Pq[row * 64 + ((6 + hi + row) & 7) * 8 + sub] = f2bs(p3);
    }

    short8 pa[2];
    for (int f = 0; f < 2; f++)
      pa[f] = *reinterpret_cast<const short8*>(
          Pq + n16 * 64 + ((quad + 4 * f + n16) & 7) * 8);

    for (int ntd = 0; ntd < 4; ntd++) {
      const short* vs = Vp + (size_t)(ntd * 16 + n16) * 1024 + k0 + quad * 8;
      short8 v0 = *reinterpret_cast<const short8*>(vs);
      short8 v1 = *reinterpret_cast<const short8*>(vs + 32);
      O[ntd] = MFMA(pa[0], v0, O[ntd]);
      O[ntd] = MFMA(pa[1], v1, O[ntd]);
    }
  }

  // epilogue: reduce l across the 16-lane row group, write [seq][ch] bf16
  for (int r = 0; r < 4; r++) {
    float s = l[r];
    s += __shfl_xor(s, 1);
    s += __shfl_xor(s, 2);
    s += __shfl_xor(s, 4);
    s += __shfl_xor(s, 8);
    l[r] = 1.0f / s;
  }
  for (int ntd = 0; ntd < 4; ntd++)
    for (int r = 0; r < 4; r++) {
      int q = q0 + quad * 4 + r;
      int ch = h * 64 + ntd * 16 + n16;
      attnT[((size_t)b * 1024 + q) * 512 + ch] = f2bs(O[ntd][r] * l[r]);
    }
}

// ---------------------------------------------------------------------------
// Kernel 4: LDS-free projection GEMM + bias + residual, fp32 out.
// ---------------------------------------------------------------------------
__global__ __launch_bounds__(256) void gemm_out(
    const short* __restrict__ Wb, const short* __restrict__ Xt,
    const float* __restrict__ bias, const float* __restrict__ resid,
    float* __restrict__ out) {
  int bx = blockIdx.x, by = blockIdx.y, bb = blockIdx.z;
  int m0 = by * 128, n0 = bx * 128;
  int t = threadIdx.x;
  int w = t >> 6, lane = t & 63, n16 = lane & 15, quad = lane >> 4;
  int wm = (w >> 1) * 64, wn = (w & 1) * 64;

  const short* Ab[4];
  const short* Bb[4];
  for (int im = 0; im < 4; im++)
    Ab[im] = Wb + (size_t)(m0 + wm + im * 16 + n16) * 512 + quad * 8;
  const short* Xb = Xt + (size_t)bb * 1024 * 512;
  for (int in = 0; in < 4; in++)
    Bb[in] = Xb + (size_t)(n0 + wn + in * 16 + n16) * 512 + quad * 8;

  floatx4 acc[4][4];
  for (int i = 0; i < 4; i++)
    for (int j = 0; j < 4; j++) acc[i][j] = (floatx4){0.f, 0.f, 0.f, 0.f};

#pragma unroll 2
  for (int kk = 0; kk < 512; kk += 32) {
    short8 a[4], b[4];
    for (int im = 0; im < 4; im++)
      a[im] = *reinterpret_cast<const short8*>(Ab[im] + kk);
    for (int in = 0; in < 4; in++)
      b[in] = *reinterpret_cast<const short8*>(Bb[in] + kk);
    for (int im = 0; im < 4; im++)
      for (int in = 0; in < 4; in++)
        acc[im][in] = MFMA(a[im], b[in], acc[im][in]);
  }

  for (int im = 0; im < 4; im++) {
    int m = m0 + wm + im * 16 + quad * 4;
    float4 bi = *reinterpret_cast<const float4*>(&bias[m]);
    for (int in = 0; in < 4; in++) {
      int nn = n0 + wn + in * 16 + n16;
      size_t idx = ((size_t)bb * 512 + m) * 1024 + nn;
      out[idx]        = acc[im][in][0] + bi.x + resid[idx];
      out[idx + 1024] = acc[im][in][1] + bi.y + resid[idx + 1024];
      out[idx + 2048] = acc[im][in][2] + bi.z + resid[idx + 2048];
      out[idx + 3072] = acc[im][in][3] + bi.w + resid[idx + 3072];
    }
  }
}

// ---------------------------------------------------------------------------
extern "C" void kernel_launch(void* const* d_in, const int* in_sizes, int n_in,
                              void* d_out, int out_size, void* d_ws, size_t ws_size,
                              hipStream_t stream) {
  const float* x     = (const float*)d_in[0];
  const float* gamma = (const float*)d_in[1];
  const float* beta  = (const float*)d_in[2];
  const float* w_in  = (const float*)d_in[3];
  const float* b_in  = (const float*)d_in[4];
  const float* w_out = (const float*)d_in[5];
  const float* b_out = (const float*)d_in[6];
  float* out = (float*)d_out;

  char* ws = (char*)d_ws;
  short* ht    = (short*)ws;                    //  8 MiB [8][1024][512]
  short* Qt    = (short*)(ws + (8u  << 20));    //  8 MiB [64][1024][64]
  short* Kt    = (short*)(ws + (16u << 20));    //  8 MiB [64][1024][64]
  short* Vn    = (short*)(ws + (24u << 20));    //  8 MiB [8][512][1024]
  short* attnT = (short*)(ws + (32u << 20));    //  8 MiB [8][1024][512]
  short* wbf1  = (short*)(ws + (40u << 20));    //  1.5 MiB
  short* wbf2  = (short*)(ws + (42u << 20));    //  0.5 MiB
  float2* stats = (float2*)(ws + (44u << 20));  //  2 KiB [256]

  cast_f2b<<<(1536 * 512) / 1024, 256, 0, stream>>>(w_in, wbf1);
  cast_f2b<<<(512 * 512) / 1024, 256, 0, stream>>>(w_out, wbf2);
  gn_stats<<<B_ * NG, 256, 0, stream>>>(x, stats);
  gn_apply<<<dim3(16, 8, B_), 256, 0, stream>>>(x, stats, gamma, beta, ht);
  gemm_qkv<<<dim3(8, 12, B_), 256, 0, stream>>>(wbf1, ht, b_in, Qt, Kt, Vn);
  attn_mfma<<<16 * 64, 256, 0, stream>>>(Qt, Kt, Vn, attnT);
  gemm_out<<<dim3(8, 4, B_), 256, 0, stream>>>(wbf2, attnT, b_out, x, out);
}

// Round 9
// 251.466 us; speedup vs baseline: 1.1186x; 1.1186x over previous
//
#include <hip/hip_runtime.h>
#include <hip/hip_bf16.h>

// Problem dims (fixed by reference)
#define B_    8
#define C_    512
#define HW_   1024     // H*W = 32*32
#define NG    32
#define GCH   16
#define EPSV  1e-6f

typedef __attribute__((ext_vector_type(8))) short short8;   // 8 bf16 (4 VGPRs)
typedef __attribute__((ext_vector_type(4))) short short4v;  // 4 bf16
typedef __attribute__((ext_vector_type(4))) float floatx4;  // MFMA C/D

static __device__ __forceinline__ short f2bs(float f) {
  return __builtin_bit_cast(short, __float2bfloat16(f));
}
static __device__ __forceinline__ short4v pack4(float a, float b, float c, float d) {
  return (short4v){f2bs(a), f2bs(b), f2bs(c), f2bs(d)};
}
#define MFMA(a, b, c) __builtin_amdgcn_mfma_f32_16x16x32_bf16((a), (b), (c), 0, 0, 0)

// ---------------------------------------------------------------------------
// fp32 -> bf16 cast (weights); 4 elems/thread
// ---------------------------------------------------------------------------
__global__ __launch_bounds__(256) void cast_f2b(const float* __restrict__ s,
                                                short* __restrict__ d) {
  int i = blockIdx.x * 256 + threadIdx.x;
  float4 v = reinterpret_cast<const float4*>(s)[i];
  reinterpret_cast<short4v*>(d)[i] = pack4(v.x, v.y, v.z, v.w);
}

// ---------------------------------------------------------------------------
// Kernel 1a: GroupNorm stats.  One block per (b, group) -> {mean, rsig}.
// ---------------------------------------------------------------------------
__global__ __launch_bounds__(256) void gn_stats(
    const float* __restrict__ x, float2* __restrict__ stats) {
  int bg = blockIdx.x;
  const int n = GCH * HW_;       // 16384
  const float* xp = x + (size_t)bg * n;
  int t = threadIdx.x;

  float s = 0.f, ss = 0.f;
  for (int i = t; i < n / 4; i += 256) {   // i indexes float4s
    float4 v = *reinterpret_cast<const float4*>(xp + i * 4);
    s  += (v.x + v.y) + (v.z + v.w);
    ss += (v.x * v.x + v.y * v.y) + (v.z * v.z + v.w * v.w);
  }
  for (int o = 32; o > 0; o >>= 1) {
    s  += __shfl_down(s, o);
    ss += __shfl_down(ss, o);
  }
  __shared__ float rs_[4], rss_[4];
  int wid = t >> 6, lane = t & 63;
  if (lane == 0) { rs_[wid] = s; rss_[wid] = ss; }
  __syncthreads();
  if (t == 0) {
    float stot  = rs_[0] + rs_[1] + rs_[2] + rs_[3];
    float sstot = rss_[0] + rss_[1] + rss_[2] + rss_[3];
    float mean = stot / (float)n;
    float var  = sstot / (float)n - mean * mean;
    stats[bg] = make_float2(mean, rsqrtf(var + EPSV));
  }
}

// ---------------------------------------------------------------------------
// Kernel 1b: normalize + transpose -> ht[b][seq][ch] bf16.
// Block = (seq-tile 64, ch-tile 64, b).  LDS float[64][65].
// ---------------------------------------------------------------------------
__global__ __launch_bounds__(256) void gn_apply(
    const float* __restrict__ x, const float2* __restrict__ stats,
    const float* __restrict__ gamma, const float* __restrict__ beta,
    short* __restrict__ ht) {
  __shared__ float Ls[64 * 65];
  int s0 = blockIdx.x * 64, ch0 = blockIdx.y * 64, b = blockIdx.z;
  int t = threadIdx.x;

  for (int i = 0; i < 4; i++) {
    int lin = t + i * 256;           // 64 rows x 16 float4
    int r = lin >> 4, c4 = lin & 15;
    int ch = ch0 + r;
    float2 st = stats[b * NG + (ch >> 4)];
    float ga = gamma[ch] * st.y;     // fold rsig into gamma
    float be = beta[ch] - st.x * ga;
    float4 v = *reinterpret_cast<const float4*>(
        x + ((size_t)(b * C_ + ch)) * HW_ + s0 + c4 * 4);
    Ls[r * 65 + c4 * 4 + 0] = v.x * ga + be;
    Ls[r * 65 + c4 * 4 + 1] = v.y * ga + be;
    Ls[r * 65 + c4 * 4 + 2] = v.z * ga + be;
    Ls[r * 65 + c4 * 4 + 3] = v.w * ga + be;
  }
  __syncthreads();
  for (int i = 0; i < 4; i++) {
    int lin = t + i * 256;           // 64 seq x 16 short4
    int sq = lin >> 4, cq = lin & 15;
    float a0 = Ls[(cq * 4 + 0) * 65 + sq];
    float a1 = Ls[(cq * 4 + 1) * 65 + sq];
    float a2 = Ls[(cq * 4 + 2) * 65 + sq];
    float a3 = Ls[(cq * 4 + 3) * 65 + sq];
    *reinterpret_cast<short4v*>(
        ht + ((size_t)b * 1024 + s0 + sq) * 512 + ch0 + cq * 4) =
        pack4(a0, a1, a2, a3);
  }
}

// ---------------------------------------------------------------------------
// Kernel 2: LDS-free MFMA QKV GEMM.
//   Output: m<512 -> Qt[b][h][seq][64] (x 0.125*log2e folded -> exp2 softmax),
//           m<1024 -> Kt same, m>=1024 -> Vn[b][ch][seq] natural.
// ---------------------------------------------------------------------------
__global__ __launch_bounds__(256) void gemm_qkv(
    const short* __restrict__ Wb, const short* __restrict__ ht,
    const float* __restrict__ bias,
    short* __restrict__ Qt, short* __restrict__ Kt, short* __restrict__ Vn) {
  int bx = blockIdx.x, by = blockIdx.y, bb = blockIdx.z;
  int m0 = by * 128, n0 = bx * 128;
  int t = threadIdx.x;
  int w = t >> 6, lane = t & 63, n16 = lane & 15, quad = lane >> 4;
  int wm = (w >> 1) * 64, wn = (w & 1) * 64;

  const short* Ab[4];
  const short* Bb[4];
  for (int im = 0; im < 4; im++)
    Ab[im] = Wb + (size_t)(m0 + wm + im * 16 + n16) * 512 + quad * 8;
  const short* Xb = ht + (size_t)bb * 1024 * 512;
  for (int in = 0; in < 4; in++)
    Bb[in] = Xb + (size_t)(n0 + wn + in * 16 + n16) * 512 + quad * 8;

  floatx4 acc[4][4];
  for (int i = 0; i < 4; i++)
    for (int j = 0; j < 4; j++) acc[i][j] = (floatx4){0.f, 0.f, 0.f, 0.f};

#pragma unroll 2
  for (int kk = 0; kk < 512; kk += 32) {
    short8 a[4], b[4];
    for (int im = 0; im < 4; im++)
      a[im] = *reinterpret_cast<const short8*>(Ab[im] + kk);
    for (int in = 0; in < 4; in++)
      b[in] = *reinterpret_cast<const short8*>(Bb[in] + kk);
    for (int im = 0; im < 4; im++)
      for (int in = 0; in < 4; in++)
        acc[im][in] = MFMA(a[im], b[in], acc[im][in]);
  }

  if (m0 < 1024) {                 // Q or K: transposed store [seq][d]
    const bool isQ = (m0 < 512);
    short* base = isQ ? Qt : Kt;
    // Q scale = 1/sqrt(64) * log2(e)  (softmax computed in base 2)
    const float sc = isQ ? 0.180336880111120426f : 1.0f;
    for (int im = 0; im < 4; im++) {
      int m = m0 + wm + im * 16 + quad * 4;
      int hh = (m >> 6) & 7, d0 = m & 63;
      float4 bi = *reinterpret_cast<const float4*>(&bias[m]);
      short* hb = base + (size_t)(bb * 8 + hh) * 1024 * 64 + d0;
      for (int in = 0; in < 4; in++) {
        int nn = n0 + wn + in * 16 + n16;
        *reinterpret_cast<short4v*>(hb + (size_t)nn * 64) =
            pack4((acc[im][in][0] + bi.x) * sc, (acc[im][in][1] + bi.y) * sc,
                  (acc[im][in][2] + bi.z) * sc, (acc[im][in][3] + bi.w) * sc);
      }
    }
  } else {                         // V: natural store [ch][seq]
    for (int im = 0; im < 4; im++) {
      int m = m0 + wm + im * 16 + quad * 4;
      float4 bi = *reinterpret_cast<const float4*>(&bias[m]);
      int ch = m - 1024;
      for (int in = 0; in < 4; in++) {
        int nn = n0 + wn + in * 16 + n16;
        short* vp = Vn + (size_t)(bb * 512 + ch) * 1024 + nn;
        vp[0]    = f2bs(acc[im][in][0] + bi.x);
        vp[1024] = f2bs(acc[im][in][1] + bi.y);
        vp[2048] = f2bs(acc[im][in][2] + bi.z);
        vp[3072] = f2bs(acc[im][in][3] + bi.w);
      }
    }
  }
}

// ---------------------------------------------------------------------------
// Kernel 3: barrier-free MFMA attention.
// 128-thread blocks (2 waves), 32 q rows/wave (2 qt chains -> 2x ILP/wave),
// grid 1024 with blk = qb*64 + (b*8+h): blk%8 = h keeps each head's K/V in
// one XCD L2 (proven: FETCH 12 MB).  8 blocks/CU = 4 waves/SIMD x 2 chains.
// Softmax in base 2, no max subtraction; P via per-wave swizzled LDS.
// ---------------------------------------------------------------------------
__global__ __launch_bounds__(128, 4) void attn_mfma(
    const short* __restrict__ Qt, const short* __restrict__ Kt,
    const short* __restrict__ Vn, short* __restrict__ attnT) {
  __shared__ short Ps[2][2][2][1024];   // [wave][kt&1][qt][16*64]  16 KB
  int blk = blockIdx.x;                 // qb*64 + b*8 + h
  int bh = blk & 63, qb = blk >> 6;     // qb 0..15
  int b = bh >> 3, h = bh & 7;
  int t = threadIdx.x;
  int w = t >> 6, lane = t & 63, n16 = lane & 15, quad = lane >> 4;
  int q0 = qb * 64 + w * 32;

  const short* Qp = Qt + (size_t)bh * 1024 * 64;
  const short* Kp = Kt + (size_t)bh * 1024 * 64;
  const short* Vp = Vn + (size_t)(b * 512 + h * 64) * 1024;

  short8 qa[2][2];
  for (int qt = 0; qt < 2; qt++)
    for (int f = 0; f < 2; f++)
      qa[qt][f] = *reinterpret_cast<const short8*>(
          Qp + (size_t)(q0 + qt * 16 + n16) * 64 + f * 32 + quad * 8);

  floatx4 O[2][4];
  float l[2][4];
  for (int qt = 0; qt < 2; qt++)
    for (int i = 0; i < 4; i++) {
      O[qt][i] = (floatx4){0.f, 0.f, 0.f, 0.f};
      l[qt][i] = 0.f;
    }

  int sub = n16 & 7, hi = n16 >> 3;
  for (int kt = 0; kt < 16; kt++) {
    int k0 = kt * 64;
    short8 kf[4][2];
    for (int nt = 0; nt < 4; nt++)
      for (int f = 0; f < 2; f++)
        kf[nt][f] = *reinterpret_cast<const short8*>(
            Kp + (size_t)(k0 + nt * 16 + n16) * 64 + f * 32 + quad * 8);

    short* Pb = &Ps[w][kt & 1][0][0];
    for (int qt = 0; qt < 2; qt++) {
      floatx4 S[4];
      for (int nt = 0; nt < 4; nt++) {
        floatx4 sa = (floatx4){0.f, 0.f, 0.f, 0.f};
        sa = MFMA(qa[qt][0], kf[nt][0], sa);
        S[nt] = MFMA(qa[qt][1], kf[nt][1], sa);
      }
      short* Pq = Pb + qt * 1024;
      for (int r = 0; r < 4; r++) {
        int row = quad * 4 + r;
        float p0 = __builtin_amdgcn_exp2f(S[0][r]);
        float p1 = __builtin_amdgcn_exp2f(S[1][r]);
        float p2 = __builtin_amdgcn_exp2f(S[2][r]);
        float p3 = __builtin_amdgcn_exp2f(S[3][r]);
        l[qt][r] += (p0 + p1) + (p2 + p3);
        Pq[row * 64 + ((0 + hi + row) & 7) * 8 + sub] = f2bs(p0);
        Pq[row * 64 + ((2 + hi + row) & 7) * 8 + sub] = f2bs(p1);
        Pq[row * 64 + ((4 + hi + row) & 7) * 8 + sub] = f2bs(p2);
        Pq[row * 64 + ((6 + hi + row) & 7) * 8 + sub] = f2bs(p3);
      }
    }

    short8 pa[2][2];
    for (int qt = 0; qt < 2; qt++)
      for (int f = 0; f < 2; f++)
        pa[qt][f] = *reinterpret_cast<const short8*>(
            Pb + qt * 1024 + n16 * 64 + ((quad + 4 * f + n16) & 7) * 8);

    for (int ntd = 0; ntd < 4; ntd++) {
      const short* vs = Vp + (size_t)(ntd * 16 + n16) * 1024 + k0 + quad * 8;
      short8 v0 = *reinterpret_cast<const short8*>(vs);
      short8 v1 = *reinterpret_cast<const short8*>(vs + 32);
      for (int qt = 0; qt < 2; qt++) {
        O[qt][ntd] = MFMA(pa[qt][0], v0, O[qt][ntd]);
        O[qt][ntd] = MFMA(pa[qt][1], v1, O[qt][ntd]);
      }
    }
  }

  // epilogue: reduce l across the 16-lane row group, write [seq][ch] bf16
  for (int qt = 0; qt < 2; qt++)
    for (int r = 0; r < 4; r++) {
      float s = l[qt][r];
      s += __shfl_xor(s, 1);
      s += __shfl_xor(s, 2);
      s += __shfl_xor(s, 4);
      s += __shfl_xor(s, 8);
      l[qt][r] = 1.0f / s;
    }
  for (int qt = 0; qt < 2; qt++)
    for (int ntd = 0; ntd < 4; ntd++)
      for (int r = 0; r < 4; r++) {
        int q = q0 + qt * 16 + quad * 4 + r;
        int ch = h * 64 + ntd * 16 + n16;
        attnT[((size_t)b * 1024 + q) * 512 + ch] = f2bs(O[qt][ntd][r] * l[qt][r]);
      }
}

// ---------------------------------------------------------------------------
// Kernel 4: LDS-free projection GEMM + bias + residual, fp32 out.
// ---------------------------------------------------------------------------
__global__ __launch_bounds__(256) void gemm_out(
    const short* __restrict__ Wb, const short* __restrict__ Xt,
    const float* __restrict__ bias, const float* __restrict__ resid,
    float* __restrict__ out) {
  int bx = blockIdx.x, by = blockIdx.y, bb = blockIdx.z;
  int m0 = by * 128, n0 = bx * 128;
  int t = threadIdx.x;
  int w = t >> 6, lane = t & 63, n16 = lane & 15, quad = lane >> 4;
  int wm = (w >> 1) * 64, wn = (w & 1) * 64;

  const short* Ab[4];
  const short* Bb[4];
  for (int im = 0; im < 4; im++)
    Ab[im] = Wb + (size_t)(m0 + wm + im * 16 + n16) * 512 + quad * 8;
  const short* Xb = Xt + (size_t)bb * 1024 * 512;
  for (int in = 0; in < 4; in++)
    Bb[in] = Xb + (size_t)(n0 + wn + in * 16 + n16) * 512 + quad * 8;

  floatx4 acc[4][4];
  for (int i = 0; i < 4; i++)
    for (int j = 0; j < 4; j++) acc[i][j] = (floatx4){0.f, 0.f, 0.f, 0.f};

#pragma unroll 2
  for (int kk = 0; kk < 512; kk += 32) {
    short8 a[4], b[4];
    for (int im = 0; im < 4; im++)
      a[im] = *reinterpret_cast<const short8*>(Ab[im] + kk);
    for (int in = 0; in < 4; in++)
      b[in] = *reinterpret_cast<const short8*>(Bb[in] + kk);
    for (int im = 0; im < 4; im++)
      for (int in = 0; in < 4; in++)
        acc[im][in] = MFMA(a[im], b[in], acc[im][in]);
  }

  for (int im = 0; im < 4; im++) {
    int m = m0 + wm + im * 16 + quad * 4;
    float4 bi = *reinterpret_cast<const float4*>(&bias[m]);
    for (int in = 0; in < 4; in++) {
      int nn = n0 + wn + in * 16 + n16;
      size_t idx = ((size_t)bb * 512 + m) * 1024 + nn;
      out[idx]        = acc[im][in][0] + bi.x + resid[idx];
      out[idx + 1024] = acc[im][in][1] + bi.y + resid[idx + 1024];
      out[idx + 2048] = acc[im][in][2] + bi.z + resid[idx + 2048];
      out[idx + 3072] = acc[im][in][3] + bi.w + resid[idx + 3072];
    }
  }
}

// ---------------------------------------------------------------------------
extern "C" void kernel_launch(void* const* d_in, const int* in_sizes, int n_in,
                              void* d_out, int out_size, void* d_ws, size_t ws_size,
                              hipStream_t stream) {
  const float* x     = (const float*)d_in[0];
  const float* gamma = (const float*)d_in[1];
  const float* beta  = (const float*)d_in[2];
  const float* w_in  = (const float*)d_in[3];
  const float* b_in  = (const float*)d_in[4];
  const float* w_out = (const float*)d_in[5];
  const float* b_out = (const float*)d_in[6];
  float* out = (float*)d_out;

  char* ws = (char*)d_ws;
  short* ht    = (short*)ws;                    //  8 MiB [8][1024][512]
  short* Qt    = (short*)(ws + (8u  << 20));    //  8 MiB [64][1024][64]
  short* Kt    = (short*)(ws + (16u << 20));    //  8 MiB [64][1024][64]
  short* Vn    = (short*)(ws + (24u << 20));    //  8 MiB [8][512][1024]
  short* attnT = (short*)(ws + (32u << 20));    //  8 MiB [8][1024][512]
  short* wbf1  = (short*)(ws + (40u << 20));    //  1.5 MiB
  short* wbf2  = (short*)(ws + (42u << 20));    //  0.5 MiB
  float2* stats = (float2*)(ws + (44u << 20));  //  2 KiB [256]

  cast_f2b<<<(1536 * 512) / 1024, 256, 0, stream>>>(w_in, wbf1);
  cast_f2b<<<(512 * 512) / 1024, 256, 0, stream>>>(w_out, wbf2);
  gn_stats<<<B_ * NG, 256, 0, stream>>>(x, stats);
  gn_apply<<<dim3(16, 8, B_), 256, 0, stream>>>(x, stats, gamma, beta, ht);
  gemm_qkv<<<dim3(8, 12, B_), 256, 0, stream>>>(wbf1, ht, b_in, Qt, Kt, Vn);
  attn_mfma<<<16 * 64, 128, 0, stream>>>(Qt, Kt, Vn, attnT);
  gemm_out<<<dim3(8, 4, B_), 256, 0, stream>>>(wbf2, attnT, b_out, x, out);
}

// Round 10
// 227.809 us; speedup vs baseline: 1.2348x; 1.1038x over previous
//
#include <hip/hip_runtime.h>
#include <hip/hip_bf16.h>

// Problem dims (fixed by reference)
#define B_    8
#define C_    512
#define HW_   1024     // H*W = 32*32
#define NG    32
#define GCH   16
#define EPSV  1e-6f

typedef __attribute__((ext_vector_type(8))) short short8;   // 8 bf16 (4 VGPRs)
typedef __attribute__((ext_vector_type(4))) short short4v;  // 4 bf16
typedef __attribute__((ext_vector_type(4))) float floatx4;  // MFMA C/D

static __device__ __forceinline__ short f2bs(float f) {
  return __builtin_bit_cast(short, __float2bfloat16(f));
}
static __device__ __forceinline__ short4v pack4(float a, float b, float c, float d) {
  return (short4v){f2bs(a), f2bs(b), f2bs(c), f2bs(d)};
}
#define MFMA(a, b, c) __builtin_amdgcn_mfma_f32_16x16x32_bf16((a), (b), (c), 0, 0, 0)

// ---------------------------------------------------------------------------
// fp32 -> bf16 cast (weights); 4 elems/thread
// ---------------------------------------------------------------------------
__global__ __launch_bounds__(256) void cast_f2b(const float* __restrict__ s,
                                                short* __restrict__ d) {
  int i = blockIdx.x * 256 + threadIdx.x;
  float4 v = reinterpret_cast<const float4*>(s)[i];
  reinterpret_cast<short4v*>(d)[i] = pack4(v.x, v.y, v.z, v.w);
}

// ---------------------------------------------------------------------------
// Kernel 1a: GroupNorm stats.  One block per (b, group) -> {mean, rsig}.
// ---------------------------------------------------------------------------
__global__ __launch_bounds__(256) void gn_stats(
    const float* __restrict__ x, float2* __restrict__ stats) {
  int bg = blockIdx.x;
  const int n = GCH * HW_;       // 16384
  const float* xp = x + (size_t)bg * n;
  int t = threadIdx.x;

  float s = 0.f, ss = 0.f;
  for (int i = t; i < n / 4; i += 256) {   // i indexes float4s
    float4 v = *reinterpret_cast<const float4*>(xp + i * 4);
    s  += (v.x + v.y) + (v.z + v.w);
    ss += (v.x * v.x + v.y * v.y) + (v.z * v.z + v.w * v.w);
  }
  for (int o = 32; o > 0; o >>= 1) {
    s  += __shfl_down(s, o);
    ss += __shfl_down(ss, o);
  }
  __shared__ float rs_[4], rss_[4];
  int wid = t >> 6, lane = t & 63;
  if (lane == 0) { rs_[wid] = s; rss_[wid] = ss; }
  __syncthreads();
  if (t == 0) {
    float stot  = rs_[0] + rs_[1] + rs_[2] + rs_[3];
    float sstot = rss_[0] + rss_[1] + rss_[2] + rss_[3];
    float mean = stot / (float)n;
    float var  = sstot / (float)n - mean * mean;
    stats[bg] = make_float2(mean, rsqrtf(var + EPSV));
  }
}

// ---------------------------------------------------------------------------
// Kernel 1b: normalize + transpose -> ht[b][seq][ch] bf16.
// Block = (seq-tile 64, ch-tile 64, b).  LDS float[64][65].
// ---------------------------------------------------------------------------
__global__ __launch_bounds__(256) void gn_apply(
    const float* __restrict__ x, const float2* __restrict__ stats,
    const float* __restrict__ gamma, const float* __restrict__ beta,
    short* __restrict__ ht) {
  __shared__ float Ls[64 * 65];
  int s0 = blockIdx.x * 64, ch0 = blockIdx.y * 64, b = blockIdx.z;
  int t = threadIdx.x;

  for (int i = 0; i < 4; i++) {
    int lin = t + i * 256;           // 64 rows x 16 float4
    int r = lin >> 4, c4 = lin & 15;
    int ch = ch0 + r;
    float2 st = stats[b * NG + (ch >> 4)];
    float ga = gamma[ch] * st.y;     // fold rsig into gamma
    float be = beta[ch] - st.x * ga;
    float4 v = *reinterpret_cast<const float4*>(
        x + ((size_t)(b * C_ + ch)) * HW_ + s0 + c4 * 4);
    Ls[r * 65 + c4 * 4 + 0] = v.x * ga + be;
    Ls[r * 65 + c4 * 4 + 1] = v.y * ga + be;
    Ls[r * 65 + c4 * 4 + 2] = v.z * ga + be;
    Ls[r * 65 + c4 * 4 + 3] = v.w * ga + be;
  }
  __syncthreads();
  for (int i = 0; i < 4; i++) {
    int lin = t + i * 256;           // 64 seq x 16 short4
    int sq = lin >> 4, cq = lin & 15;
    float a0 = Ls[(cq * 4 + 0) * 65 + sq];
    float a1 = Ls[(cq * 4 + 1) * 65 + sq];
    float a2 = Ls[(cq * 4 + 2) * 65 + sq];
    float a3 = Ls[(cq * 4 + 3) * 65 + sq];
    *reinterpret_cast<short4v*>(
        ht + ((size_t)b * 1024 + s0 + sq) * 512 + ch0 + cq * 4) =
        pack4(a0, a1, a2, a3);
  }
}

// ---------------------------------------------------------------------------
// Kernel 2: LDS-free MFMA QKV GEMM.
//   Output: m<512 -> Qt[b][h][seq][64] (x 0.125*log2e folded -> exp2 softmax),
//           m<1024 -> Kt same, m>=1024 -> Vn[b][ch][seq] natural.
// ---------------------------------------------------------------------------
__global__ __launch_bounds__(256) void gemm_qkv(
    const short* __restrict__ Wb, const short* __restrict__ ht,
    const float* __restrict__ bias,
    short* __restrict__ Qt, short* __restrict__ Kt, short* __restrict__ Vn) {
  int bx = blockIdx.x, by = blockIdx.y, bb = blockIdx.z;
  int m0 = by * 128, n0 = bx * 128;
  int t = threadIdx.x;
  int w = t >> 6, lane = t & 63, n16 = lane & 15, quad = lane >> 4;
  int wm = (w >> 1) * 64, wn = (w & 1) * 64;

  const short* Ab[4];
  const short* Bb[4];
  for (int im = 0; im < 4; im++)
    Ab[im] = Wb + (size_t)(m0 + wm + im * 16 + n16) * 512 + quad * 8;
  const short* Xb = ht + (size_t)bb * 1024 * 512;
  for (int in = 0; in < 4; in++)
    Bb[in] = Xb + (size_t)(n0 + wn + in * 16 + n16) * 512 + quad * 8;

  floatx4 acc[4][4];
  for (int i = 0; i < 4; i++)
    for (int j = 0; j < 4; j++) acc[i][j] = (floatx4){0.f, 0.f, 0.f, 0.f};

#pragma unroll 2
  for (int kk = 0; kk < 512; kk += 32) {
    short8 a[4], b[4];
    for (int im = 0; im < 4; im++)
      a[im] = *reinterpret_cast<const short8*>(Ab[im] + kk);
    for (int in = 0; in < 4; in++)
      b[in] = *reinterpret_cast<const short8*>(Bb[in] + kk);
    for (int im = 0; im < 4; im++)
      for (int in = 0; in < 4; in++)
        acc[im][in] = MFMA(a[im], b[in], acc[im][in]);
  }

  if (m0 < 1024) {                 // Q or K: transposed store [seq][d]
    const bool isQ = (m0 < 512);
    short* base = isQ ? Qt : Kt;
    // Q scale = 1/sqrt(64) * log2(e)  (softmax computed in base 2)
    const float sc = isQ ? 0.180336880111120426f : 1.0f;
    for (int im = 0; im < 4; im++) {
      int m = m0 + wm + im * 16 + quad * 4;
      int hh = (m >> 6) & 7, d0 = m & 63;
      float4 bi = *reinterpret_cast<const float4*>(&bias[m]);
      short* hb = base + (size_t)(bb * 8 + hh) * 1024 * 64 + d0;
      for (int in = 0; in < 4; in++) {
        int nn = n0 + wn + in * 16 + n16;
        *reinterpret_cast<short4v*>(hb + (size_t)nn * 64) =
            pack4((acc[im][in][0] + bi.x) * sc, (acc[im][in][1] + bi.y) * sc,
                  (acc[im][in][2] + bi.z) * sc, (acc[im][in][3] + bi.w) * sc);
      }
    }
  } else {                         // V: natural store [ch][seq]
    for (int im = 0; im < 4; im++) {
      int m = m0 + wm + im * 16 + quad * 4;
      float4 bi = *reinterpret_cast<const float4*>(&bias[m]);
      int ch = m - 1024;
      for (int in = 0; in < 4; in++) {
        int nn = n0 + wn + in * 16 + n16;
        short* vp = Vn + (size_t)(bb * 512 + ch) * 1024 + nn;
        vp[0]    = f2bs(acc[im][in][0] + bi.x);
        vp[1024] = f2bs(acc[im][in][1] + bi.y);
        vp[2048] = f2bs(acc[im][in][2] + bi.z);
        vp[3072] = f2bs(acc[im][in][3] + bi.w);
      }
    }
  }
}

// ---------------------------------------------------------------------------
// Kernel 3: barrier-free MFMA attention — R7 shape (the 67 µs config:
// grid 512, 256 threads, 4 waves x 2 qt chains of 16 q rows, 32 KB LDS,
// ~108 VGPR so all 8 K-loads stay in flight) + XCD swizzle only:
// blk = qb*64 + bh -> all 8 q-blocks of head bh are congruent mod 8 ->
// one XCD's L2 holds that head's K/V (proven FETCH drop in R8/R9).
// Softmax in base 2 (scale folded into Q), no max subtraction.
// ---------------------------------------------------------------------------
__global__ __launch_bounds__(256) void attn_mfma(
    const short* __restrict__ Qt, const short* __restrict__ Kt,
    const short* __restrict__ Vn, short* __restrict__ attnT) {
  __shared__ short Ps[4][2][2][1024];   // [wave][kt&1][qt][16*64]  32 KB
  int blk = blockIdx.x;                 // qb*64 + b*8 + h
  int bh = blk & 63, qb = blk >> 6;     // qb 0..7
  int b = bh >> 3, h = bh & 7;
  int t = threadIdx.x;
  int w = t >> 6, lane = t & 63, n16 = lane & 15, quad = lane >> 4;
  int q0 = qb * 128 + w * 32;

  const short* Qp = Qt + (size_t)bh * 1024 * 64;
  const short* Kp = Kt + (size_t)bh * 1024 * 64;
  const short* Vp = Vn + (size_t)(b * 512 + h * 64) * 1024;

  short8 qa[2][2];
  for (int qt = 0; qt < 2; qt++)
    for (int f = 0; f < 2; f++)
      qa[qt][f] = *reinterpret_cast<const short8*>(
          Qp + (size_t)(q0 + qt * 16 + n16) * 64 + f * 32 + quad * 8);

  floatx4 O[2][4];
  float l[2][4];
  for (int qt = 0; qt < 2; qt++)
    for (int i = 0; i < 4; i++) {
      O[qt][i] = (floatx4){0.f, 0.f, 0.f, 0.f};
      l[qt][i] = 0.f;
    }

  int sub = n16 & 7, hi = n16 >> 3;
  for (int kt = 0; kt < 16; kt++) {
    int k0 = kt * 64;
    short8 kf[4][2];
    for (int nt = 0; nt < 4; nt++)
      for (int f = 0; f < 2; f++)
        kf[nt][f] = *reinterpret_cast<const short8*>(
            Kp + (size_t)(k0 + nt * 16 + n16) * 64 + f * 32 + quad * 8);

    short* Pb = &Ps[w][kt & 1][0][0];
    for (int qt = 0; qt < 2; qt++) {
      floatx4 S[4];
      for (int nt = 0; nt < 4; nt++) {
        floatx4 sa = (floatx4){0.f, 0.f, 0.f, 0.f};
        sa = MFMA(qa[qt][0], kf[nt][0], sa);
        S[nt] = MFMA(qa[qt][1], kf[nt][1], sa);
      }
      short* Pq = Pb + qt * 1024;
      for (int r = 0; r < 4; r++) {
        int row = quad * 4 + r;
        float p0 = __builtin_amdgcn_exp2f(S[0][r]);
        float p1 = __builtin_amdgcn_exp2f(S[1][r]);
        float p2 = __builtin_amdgcn_exp2f(S[2][r]);
        float p3 = __builtin_amdgcn_exp2f(S[3][r]);
        l[qt][r] += (p0 + p1) + (p2 + p3);
        Pq[row * 64 + ((0 + hi + row) & 7) * 8 + sub] = f2bs(p0);
        Pq[row * 64 + ((2 + hi + row) & 7) * 8 + sub] = f2bs(p1);
        Pq[row * 64 + ((4 + hi + row) & 7) * 8 + sub] = f2bs(p2);
        Pq[row * 64 + ((6 + hi + row) & 7) * 8 + sub] = f2bs(p3);
      }
    }

    short8 pa[2][2];
    for (int qt = 0; qt < 2; qt++)
      for (int f = 0; f < 2; f++)
        pa[qt][f] = *reinterpret_cast<const short8*>(
            Pb + qt * 1024 + n16 * 64 + ((quad + 4 * f + n16) & 7) * 8);

    for (int ntd = 0; ntd < 4; ntd++) {
      const short* vs = Vp + (size_t)(ntd * 16 + n16) * 1024 + k0 + quad * 8;
      short8 v0 = *reinterpret_cast<const short8*>(vs);
      short8 v1 = *reinterpret_cast<const short8*>(vs + 32);
      for (int qt = 0; qt < 2; qt++) {
        O[qt][ntd] = MFMA(pa[qt][0], v0, O[qt][ntd]);
        O[qt][ntd] = MFMA(pa[qt][1], v1, O[qt][ntd]);
      }
    }
  }

  // epilogue: reduce l across the 16-lane row group, write [seq][ch] bf16
  for (int qt = 0; qt < 2; qt++)
    for (int r = 0; r < 4; r++) {
      float s = l[qt][r];
      s += __shfl_xor(s, 1);
      s += __shfl_xor(s, 2);
      s += __shfl_xor(s, 4);
      s += __shfl_xor(s, 8);
      l[qt][r] = 1.0f / s;
    }
  for (int qt = 0; qt < 2; qt++)
    for (int ntd = 0; ntd < 4; ntd++)
      for (int r = 0; r < 4; r++) {
        int q = q0 + qt * 16 + quad * 4 + r;
        int ch = h * 64 + ntd * 16 + n16;
        attnT[((size_t)b * 1024 + q) * 512 + ch] = f2bs(O[qt][ntd][r] * l[qt][r]);
      }
}

// ---------------------------------------------------------------------------
// Kernel 4: LDS-free projection GEMM + bias + residual, fp32 out.
// ---------------------------------------------------------------------------
__global__ __launch_bounds__(256) void gemm_out(
    const short* __restrict__ Wb, const short* __restrict__ Xt,
    const float* __restrict__ bias, const float* __restrict__ resid,
    float* __restrict__ out) {
  int bx = blockIdx.x, by = blockIdx.y, bb = blockIdx.z;
  int m0 = by * 128, n0 = bx * 128;
  int t = threadIdx.x;
  int w = t >> 6, lane = t & 63, n16 = lane & 15, quad = lane >> 4;
  int wm = (w >> 1) * 64, wn = (w & 1) * 64;

  const short* Ab[4];
  const short* Bb[4];
  for (int im = 0; im < 4; im++)
    Ab[im] = Wb + (size_t)(m0 + wm + im * 16 + n16) * 512 + quad * 8;
  const short* Xb = Xt + (size_t)bb * 1024 * 512;
  for (int in = 0; in < 4; in++)
    Bb[in] = Xb + (size_t)(n0 + wn + in * 16 + n16) * 512 + quad * 8;

  floatx4 acc[4][4];
  for (int i = 0; i < 4; i++)
    for (int j = 0; j < 4; j++) acc[i][j] = (floatx4){0.f, 0.f, 0.f, 0.f};

#pragma unroll 2
  for (int kk = 0; kk < 512; kk += 32) {
    short8 a[4], b[4];
    for (int im = 0; im < 4; im++)
      a[im] = *reinterpret_cast<const short8*>(Ab[im] + kk);
    for (int in = 0; in < 4; in++)
      b[in] = *reinterpret_cast<const short8*>(Bb[in] + kk);
    for (int im = 0; im < 4; im++)
      for (int in = 0; in < 4; in++)
        acc[im][in] = MFMA(a[im], b[in], acc[im][in]);
  }

  for (int im = 0; im < 4; im++) {
    int m = m0 + wm + im * 16 + quad * 4;
    float4 bi = *reinterpret_cast<const float4*>(&bias[m]);
    for (int in = 0; in < 4; in++) {
      int nn = n0 + wn + in * 16 + n16;
      size_t idx = ((size_t)bb * 512 + m) * 1024 + nn;
      out[idx]        = acc[im][in][0] + bi.x + resid[idx];
      out[idx + 1024] = acc[im][in][1] + bi.y + resid[idx + 1024];
      out[idx + 2048] = acc[im][in][2] + bi.z + resid[idx + 2048];
      out[idx + 3072] = acc[im][in][3] + bi.w + resid[idx + 3072];
    }
  }
}

// ---------------------------------------------------------------------------
extern "C" void kernel_launch(void* const* d_in, const int* in_sizes, int n_in,
                              void* d_out, int out_size, void* d_ws, size_t ws_size,
                              hipStream_t stream) {
  const float* x     = (const float*)d_in[0];
  const float* gamma = (const float*)d_in[1];
  const float* beta  = (const float*)d_in[2];
  const float* w_in  = (const float*)d_in[3];
  const float* b_in  = (const float*)d_in[4];
  const float* w_out = (const float*)d_in[5];
  const float* b_out = (const float*)d_in[6];
  float* out = (float*)d_out;

  char* ws = (char*)d_ws;
  short* ht    = (short*)ws;                    //  8 MiB [8][1024][512]
  short* Qt    = (short*)(ws + (8u  << 20));    //  8 MiB [64][1024][64]
  short* Kt    = (short*)(ws + (16u << 20));    //  8 MiB [64][1024][64]
  short* Vn    = (short*)(ws + (24u << 20));    //  8 MiB [8][512][1024]
  short* attnT = (short*)(ws + (32u << 20));    //  8 MiB [8][1024][512]
  short* wbf1  = (short*)(ws + (40u << 20));    //  1.5 MiB
  short* wbf2  = (short*)(ws + (42u << 20));    //  0.5 MiB
  float2* stats = (float2*)(ws + (44u << 20));  //  2 KiB [256]

  cast_f2b<<<(1536 * 512) / 1024, 256, 0, stream>>>(w_in, wbf1);
  cast_f2b<<<(512 * 512) / 1024, 256, 0, stream>>>(w_out, wbf2);
  gn_stats<<<B_ * NG, 256, 0, stream>>>(x, stats);
  gn_apply<<<dim3(16, 8, B_), 256, 0, stream>>>(x, stats, gamma, beta, ht);
  gemm_qkv<<<dim3(8, 12, B_), 256, 0, stream>>>(wbf1, ht, b_in, Qt, Kt, Vn);
  attn_mfma<<<8 * 64, 256, 0, stream>>>(Qt, Kt, Vn, attnT);
  gemm_out<<<dim3(8, 4, B_), 256, 0, stream>>>(wbf2, attnT, b_out, x, out);
}